// Round 14
// baseline (27.869 us; speedup 1.0000x reference)
//
#include <hip/hip_runtime.h>
#include <math.h>

#define NS 96
#define NSEG 95
#define LPR 16     // lanes per ray
#define SPL 6      // segments per lane (16*6 = 96 slots, slot 95 fake)
#define RPB 16     // rays per block (256 threads / 16 lanes)

__device__ __forceinline__ float fexp2(float x) { return __builtin_amdgcn_exp2f(x); }
__device__ __forceinline__ float flog2(float x) { return __builtin_amdgcn_logf(x); }

// Direct global->LDS DMA (no VGPR roundtrip, compiler-tracked in vmcnt).
__device__ __forceinline__ void cp16(void* lds, const void* g) {
    __builtin_amdgcn_global_load_lds(
        (const __attribute__((address_space(1))) unsigned int*)g,
        (__attribute__((address_space(3))) unsigned int*)lds, 16, 0, 0);
}
__device__ __forceinline__ void cp4(void* lds, const void* g) {
    __builtin_amdgcn_global_load_lds(
        (const __attribute__((address_space(1))) unsigned int*)g,
        (__attribute__((address_space(3))) unsigned int*)lds, 4, 0, 0);
}

// ---------------------------------------------------------------------------
// Single kernel, no __syncthreads. Per wave: ALL inputs for its own 4 rays
// staged via 12 coalesced LDS-DMA instructions (~120 cache lines/wave vs
// ~310 for per-lane gathers); one vmcnt(0) orders producer->consumer (wave-
// private LDS regions). Weights leave through a wave-private LDS
// redistribution -> 2 coalesced float4 stores. Per-ray depth clamp == global
// clamp (cd is a convex combination of the ray's own midpoints; sw > 0
// guaranteed by softplus > 0 and strictly sorted depths).
// ---------------------------------------------------------------------------
__global__ __launch_bounds__(256, 4) void raymarch_kernel(
    const float* __restrict__ colors,
    const float* __restrict__ densities,
    const float* __restrict__ depths,
    float* __restrict__ out_rgb,
    float* __restrict__ out_depth,
    float* __restrict__ out_w,
    int n_rays)
{
    __shared__ float scol[RPB * 288];   // 18432 B (reused for w redistribution)
    __shared__ float sdep[RPB * 96];    //  6144 B
    __shared__ float sden[RPB * 96];    //  6144 B   total 30720 B

    const int tid  = threadIdx.x;
    const int wv   = tid >> 6;
    const int lane = tid & 63;
    const int sub  = tid & 15;          // lane within ray (0..15)
    const int g    = lane >> 4;         // ray within wave (0..3)
    const int rloc = wv * 4 + g;        // ray within block
    const int base = blockIdx.x * RPB;
    const int ray  = base + rloc;
    const int wray = base + wv * 4;     // first ray of this wave
    const bool full = (wray + 4 <= n_rays);

    // ---- stage this wave's 4 rays: colors + depths + densities -------------
    if (full) {
        const float4* gq = (const float4*)colors + (size_t)wray * 72;
        float4* sq = (float4*)scol + wv * 288;
#pragma unroll
        for (int q = 0; q < 4; ++q)                  // colors: 4 x 1KB
            cp16(sq + 64 * q + lane, gq + 64 * q + lane);
        const float* gdw = colors + (size_t)wray * 288;
        float* sdw = scol + wv * 1152;
        cp4(sdw + 1024 + lane, gdw + 1024 + lane);   // colors tail 512B
        cp4(sdw + 1088 + lane, gdw + 1088 + lane);

        const float4* gd = (const float4*)depths + (size_t)wray * 24;
        float4* sd4 = (float4*)sdep + wv * 96;
        cp16(sd4 + lane, gd + lane);                 // depths: 1KB
        const float* gdd = depths + (size_t)wray * 96;
        float* sdd = sdep + wv * 384;
        cp4(sdd + 256 + lane, gdd + 256 + lane);     // depths tail 512B
        cp4(sdd + 320 + lane, gdd + 320 + lane);

        const float4* gn = (const float4*)densities + (size_t)wray * 24;
        float4* sn4 = (float4*)sden + wv * 96;
        cp16(sn4 + lane, gn + lane);                 // densities: 1KB
        const float* gnn = densities + (size_t)wray * 96;
        float* snn = sden + wv * 384;
        cp4(snn + 256 + lane, gnn + 256 + lane);     // densities tail 512B
        cp4(snn + 320 + lane, gnn + 320 + lane);
    } else {
        // tail wave (rare): per-lane staging of valid rays
        int r = wray + g;
        if (r < n_rays) {
            for (int t = sub; t < 288; t += 16)
                scol[wv * 1152 + g * 288 + t] = colors[(size_t)r * 288 + t];
            for (int t = sub; t < 96; t += 16) {
                sdep[wv * 384 + g * 96 + t] = depths[(size_t)r * 96 + t];
                sden[wv * 384 + g * 96 + t] = densities[(size_t)r * 96 + t];
            }
        }
    }

    // ---- single drain: all DMA landed in this wave's LDS regions -----------
    asm volatile("s_waitcnt vmcnt(0)" ::: "memory");
    __builtin_amdgcn_sched_barrier(0);

    if (ray >= n_rays) return;

    const int s0 = sub * SPL;           // first sample (0,6,..,90)
    const bool lastl = (sub == LPR - 1);

    const float* ldep = sdep + wv * 384 + g * 96 + s0;
    const float* lden = sden + wv * 384 + g * 96 + s0;

    // ---- depths / densities from LDS ---------------------------------------
    float d[7], nd[7];
    {
        float2 v;
        v = *(const float2*)(ldep + 0); d[0] = v.x; d[1] = v.y;
        v = *(const float2*)(ldep + 2); d[2] = v.x; d[3] = v.y;
        v = *(const float2*)(ldep + 4); d[4] = v.x; d[5] = v.y;
        d[6] = ldep[lastl ? 5 : 6];     // lastl: d[6]=d[5] -> delta=0 -> w=0
        v = *(const float2*)(lden + 0); nd[0] = v.x; nd[1] = v.y;
        v = *(const float2*)(lden + 2); nd[2] = v.x; nd[3] = v.y;
        v = *(const float2*)(lden + 4); nd[4] = v.x; nd[5] = v.y;
        nd[6] = lden[lastl ? 5 : 6];
    }

    // ---- e_j = exp(-softplus(mid-1)*delta), native exp2/log2 ---------------
    const float LOG2E = 1.4426950408889634f;
    float e[SPL];
#pragma unroll
    for (int j = 0; j < SPL; ++j) {
        float delta = d[j + 1] - d[j];
        float x = (nd[j] + nd[j + 1]) * 0.5f - 1.0f;
        float sp2 = fmaxf(x, 0.f) * LOG2E + flog2(1.0f + fexp2(-fabsf(x) * LOG2E));
        e[j] = fexp2(-delta * sp2);
    }

    // ---- local product + width-16 inclusive scan -> exclusive T ------------
    float P = 1.0f;
#pragma unroll
    for (int j = 0; j < SPL; ++j) P *= (e[j] + 1e-10f);
    float inc = P;
#pragma unroll
    for (int off = 1; off < LPR; off <<= 1) {
        float t = __shfl_up(inc, off, LPR);
        if (sub >= off) inc *= t;
    }
    float Tex = __shfl_up(inc, 1, LPR);
    if (sub == 0) Tex = 1.0f;

    // ---- weights, sw/sd composites -----------------------------------------
    float w[SPL];
    float sw = 0.f, sd = 0.f;
    {
        float T = Tex;
#pragma unroll
        for (int j = 0; j < SPL; ++j) {
            w[j] = (1.0f - e[j]) * T;
            T *= (e[j] + 1e-10f);
            sw += w[j];
            sd += w[j] * (d[j] + d[j + 1]);   // x0.5 folded into epilogue
        }
    }

    // ---- colors from this wave's LDS region --------------------------------
    const float* lcol = scol + wv * 1152 + g * 288 + 3 * s0;
    float c[21];
#pragma unroll
    for (int q = 0; q < 9; ++q) {
        float2 v = *(const float2*)(lcol + 2 * q);
        c[2 * q] = v.x; c[2 * q + 1] = v.y;
    }
    {
        float2 v = *(const float2*)(lcol + (lastl ? 16 : 18));
        c[18] = v.x; c[19] = v.y;          // lastl: dup of c[16..17], w=0 kills
        c[20] = lcol[lastl ? 17 : 20];
    }

    // ---- rgb partials ------------------------------------------------------
    float sr = 0.f, sg = 0.f, sb = 0.f;
#pragma unroll
    for (int j = 0; j < SPL; ++j) {
        sr += w[j] * (c[3 * j + 0] + c[3 * j + 3]);
        sg += w[j] * (c[3 * j + 1] + c[3 * j + 4]);
        sb += w[j] * (c[3 * j + 2] + c[3 * j + 5]);
    }

    // ---- width-16 butterflies for the 5 composites -------------------------
#pragma unroll
    for (int off = 1; off < LPR; off <<= 1) {
        sw += __shfl_xor(sw, off, LPR);
        sd += __shfl_xor(sd, off, LPR);
        sr += __shfl_xor(sr, off, LPR);
        sg += __shfl_xor(sg, off, LPR);
        sb += __shfl_xor(sb, off, LPR);
    }

    // ---- weights out: redistribute via (dead) color region -> 2 f4 stores --
    if (full) {
        float* W = scol + wv * 1152;    // wave-private; colors already consumed
#pragma unroll
        for (int j = 0; j < SPL; ++j)
            if (!(lastl && j == SPL - 1)) W[g * NSEG + s0 + j] = w[j];
        __builtin_amdgcn_sched_barrier(0);   // keep write->read order tight
        const float4* W4 = (const float4*)W;
        float4* go = (float4*)(out_w + (size_t)wray * NSEG);  // 380 contiguous
        go[lane] = W4[lane];
        if (lane < 31) go[64 + lane] = W4[64 + lane];
    } else {
        float* wg = out_w + (size_t)ray * NSEG + s0;
        *(float2*)(wg + 0) = make_float2(w[0], w[1]);
        *(float2*)(wg + 2) = make_float2(w[2], w[3]);
        if (!lastl) *(float2*)(wg + 4) = make_float2(w[4], w[5]);
        else        wg[4] = w[4];
    }

    // ---- epilogue ----------------------------------------------------------
    if (sub == 0) {
        float rmin = sdep[wv * 384 + g * 96 + 0];    // broadcast LDS reads
        float rmax = sdep[wv * 384 + g * 96 + 95];
        float cd = (0.5f * sd) / sw;
        if (isnan(cd)) cd = __int_as_float(0x7F800000);
        cd = fminf(fmaxf(cd, rmin), rmax);
        out_depth[ray] = cd;
        out_rgb[(size_t)ray * 3 + 0] = sr - 1.0f;    // (0.5*sr)*2 - 1
        out_rgb[(size_t)ray * 3 + 1] = sg - 1.0f;
        out_rgb[(size_t)ray * 3 + 2] = sb - 1.0f;
    }
}

// ---------------------------------------------------------------------------
extern "C" void kernel_launch(void* const* d_in, const int* in_sizes, int n_in,
                              void* d_out, int out_size, void* d_ws, size_t ws_size,
                              hipStream_t stream) {
    const float* colors    = (const float*)d_in[0];
    const float* densities = (const float*)d_in[1];
    const float* depths    = (const float*)d_in[2];

    const int n_rays = in_sizes[1] / NS;

    float* out       = (float*)d_out;
    float* out_rgb   = out;
    float* out_depth = out + (size_t)n_rays * 3;
    float* out_w     = out + (size_t)n_rays * 4;

    hipLaunchKernelGGL(raymarch_kernel,
                       dim3((n_rays + RPB - 1) / RPB), dim3(256), 0, stream,
                       colors, densities, depths,
                       out_rgb, out_depth, out_w, n_rays);
}

// Round 15
// 26.806 us; speedup vs baseline: 1.0397x; 1.0397x over previous
//
#include <hip/hip_runtime.h>
#include <math.h>

#define NS 96
#define NSEG 95
#define LPR 16     // lanes per ray
#define SPL 6      // segments per lane (16*6 = 96 slots, slot 95 fake)
#define RPB 16     // rays per block (256 threads / 16 lanes)

__device__ __forceinline__ float fexp2(float x) { return __builtin_amdgcn_exp2f(x); }
__device__ __forceinline__ float flog2(float x) { return __builtin_amdgcn_logf(x); }

// Direct global->LDS DMA (no VGPR roundtrip, counted in vmcnt).
__device__ __forceinline__ void cp16(void* lds, const void* g) {
    __builtin_amdgcn_global_load_lds(
        (const __attribute__((address_space(1))) unsigned int*)g,
        (__attribute__((address_space(3))) unsigned int*)lds, 16, 0, 0);
}
__device__ __forceinline__ void cp4(void* lds, const void* g) {
    __builtin_amdgcn_global_load_lds(
        (const __attribute__((address_space(1))) unsigned int*)g,
        (__attribute__((address_space(3))) unsigned int*)lds, 4, 0, 0);
}

// Inline-asm volatile loads: cannot be sunk -> forced MLP (R12 proven).
__device__ __forceinline__ float2 gl2(const float* p) {
    float2 r;
    asm volatile("global_load_dwordx2 %0, %1, off" : "=v"(r) : "v"(p));
    return r;
}
__device__ __forceinline__ float gl1(const float* p) {
    float r;
    asm volatile("global_load_dword %0, %1, off" : "=v"(r) : "v"(p));
    return r;
}

// ---------------------------------------------------------------------------
// Single kernel, no __syncthreads. Pipeline: issue 8 dep/den register loads,
// then 6 color LDS-DMAs; counted wait vmcnt(6) (VMEM returns are FIFO) lets
// ALL of phase A (transcendentals/scan/weights) run under the color latency;
// vmcnt(0) only before the color-consuming phase B. Per-ray depth clamp ==
// global clamp (cd is a convex combination of the ray's own midpoints;
// sw > 0 guaranteed: softplus > 0, depths strictly sorted).
// ---------------------------------------------------------------------------
__global__ __launch_bounds__(256, 8) void raymarch_kernel(
    const float* __restrict__ colors,
    const float* __restrict__ densities,
    const float* __restrict__ depths,
    float* __restrict__ out_rgb,
    float* __restrict__ out_depth,
    float* __restrict__ out_w,
    int n_rays)
{
    __shared__ float scol[RPB * 288];   // 18432 B -> 8 blocks/CU possible

    const int tid  = threadIdx.x;
    const int wv   = tid >> 6;
    const int lane = tid & 63;
    const int sub  = tid & 15;          // lane within ray (0..15)
    const int rloc = tid >> 4;          // ray within block (0..15)
    const int base = blockIdx.x * RPB;
    const int ray  = base + rloc;
    const int rc   = min(ray, n_rays - 1);
    const bool safe = (ray < n_rays);
    const int wray = base + wv * 4;     // first ray of this wave
    const bool full = (wray + 4 <= n_rays);

    const int s0 = sub * SPL;           // first sample (0,6,..,90)
    const bool lastl = (sub == LPR - 1);

    const float* dep = depths    + (size_t)rc * NS + s0;
    const float* den = densities + (size_t)rc * NS + s0;

    // ---- issue dep/den register loads FIRST (8 VMEM, oldest in FIFO) -------
    float2 dv0 = gl2(dep + 0);
    float2 dv1 = gl2(dep + 2);
    float2 dv2 = gl2(dep + 4);
    float  d6  = gl1(dep + (lastl ? 5 : 6));  // lastl: delta=0 -> w=0
    float2 nv0 = gl2(den + 0);
    float2 nv1 = gl2(den + 2);
    float2 nv2 = gl2(den + 4);
    float  n6  = gl1(den + (lastl ? 5 : 6));

    // ---- then color staging (6 DMA, youngest in FIFO) ----------------------
    if (full) {
        const float4* gq = (const float4*)colors + (size_t)wray * 72;
        float4* sq = (float4*)scol + wv * 288;
#pragma unroll
        for (int q = 0; q < 4; ++q)                 // 4 x 1KB contiguous
            cp16(sq + 64 * q + lane, gq + 64 * q + lane);
        const float* gdw = colors + (size_t)wray * 288;
        float* sdw = scol + wv * 1152;
        cp4(sdw + 1024 + lane, gdw + 1024 + lane);  // tail 512B
        cp4(sdw + 1088 + lane, gdw + 1088 + lane);
        // counted wait: <=6 outstanding => the 8 dep/den loads completed
        asm volatile("s_waitcnt vmcnt(6)" ::: "memory");
    } else {
        // tail wave (none when n_rays % 16 == 0): per-lane staging
        int r = wray + (lane >> 4);
        if (r < n_rays)
            for (int t = sub; t < 288; t += 16)
                scol[wv * 1152 + (lane >> 4) * 288 + t] = colors[(size_t)r * 288 + t];
        asm volatile("s_waitcnt vmcnt(0)" ::: "memory");
    }
    __builtin_amdgcn_sched_barrier(0);   // rule #18: pin consumers below wait

    // ======================= Phase A (colors still in flight) ===============
    float d[7], nd[7];
    d[0] = dv0.x; d[1] = dv0.y; d[2] = dv1.x; d[3] = dv1.y;
    d[4] = dv2.x; d[5] = dv2.y; d[6] = d6;
    nd[0] = nv0.x; nd[1] = nv0.y; nd[2] = nv1.x; nd[3] = nv1.y;
    nd[4] = nv2.x; nd[5] = nv2.y; nd[6] = n6;

    const float LOG2E = 1.4426950408889634f;
    float e[SPL];
#pragma unroll
    for (int j = 0; j < SPL; ++j) {
        float delta = d[j + 1] - d[j];
        float x = (nd[j] + nd[j + 1]) * 0.5f - 1.0f;
        float sp2 = fmaxf(x, 0.f) * LOG2E + flog2(1.0f + fexp2(-fabsf(x) * LOG2E));
        e[j] = fexp2(-delta * sp2);
    }

    float P = 1.0f;
#pragma unroll
    for (int j = 0; j < SPL; ++j) P *= (e[j] + 1e-10f);
    float inc = P;
#pragma unroll
    for (int off = 1; off < LPR; off <<= 1) {
        float t = __shfl_up(inc, off, LPR);
        if (sub >= off) inc *= t;
    }
    float Tex = __shfl_up(inc, 1, LPR);
    if (sub == 0) Tex = 1.0f;

    float w[SPL];
    float sw = 0.f, sd = 0.f;
    {
        float T = Tex;
#pragma unroll
        for (int j = 0; j < SPL; ++j) {
            w[j] = (1.0f - e[j]) * T;
            T *= (e[j] + 1e-10f);
            sw += w[j];
            sd += w[j] * (d[j] + d[j + 1]);   // x0.5 folded into epilogue
        }
    }

    // per-ray clamp bounds while ALL lanes active
    float rmax = __shfl(d[6], LPR - 1, LPR);   // lane15's d[6] = sample 95
    float rmin = __shfl(d[0], 0, LPR);         // lane0's d[0] = sample 0

    // ---- weight stores: 3x float2 (8B-aligned: s0*4 = 24B*sub) -------------
    if (safe) {
        float* wg = out_w + (size_t)ray * NSEG + s0;
        *(float2*)(wg + 0) = make_float2(w[0], w[1]);
        *(float2*)(wg + 2) = make_float2(w[2], w[3]);
        if (!lastl) *(float2*)(wg + 4) = make_float2(w[4], w[5]);
        else        wg[4] = w[4];              // slot 95 doesn't exist
    }

    // ---- drain colors into LDS, then consume -------------------------------
    if (full) {
        asm volatile("s_waitcnt vmcnt(0)" ::: "memory");
        __builtin_amdgcn_sched_barrier(0);
    }

    // ======================= Phase B ========================================
    const float* lcol = scol + wv * 1152 + (lane >> 4) * 288 + 3 * s0;
    float c[21];
#pragma unroll
    for (int q = 0; q < 9; ++q) {
        float2 v = *(const float2*)(lcol + 2 * q);
        c[2 * q] = v.x; c[2 * q + 1] = v.y;
    }
    {
        float2 v = *(const float2*)(lcol + (lastl ? 16 : 18));
        c[18] = v.x; c[19] = v.y;          // lastl: dup of c[16..17], w=0 kills
        c[20] = lcol[lastl ? 17 : 20];
    }

    float sr = 0.f, sg = 0.f, sb = 0.f;
#pragma unroll
    for (int j = 0; j < SPL; ++j) {
        sr += w[j] * (c[3 * j + 0] + c[3 * j + 3]);
        sg += w[j] * (c[3 * j + 1] + c[3 * j + 4]);
        sb += w[j] * (c[3 * j + 2] + c[3 * j + 5]);
    }

#pragma unroll
    for (int off = 1; off < LPR; off <<= 1) {
        sw += __shfl_xor(sw, off, LPR);
        sd += __shfl_xor(sd, off, LPR);
        sr += __shfl_xor(sr, off, LPR);
        sg += __shfl_xor(sg, off, LPR);
        sb += __shfl_xor(sb, off, LPR);
    }

    // ---- epilogue ----------------------------------------------------------
    if (sub == 0 && safe) {
        float cd = (0.5f * sd) / sw;
        if (isnan(cd)) cd = __int_as_float(0x7F800000);
        cd = fminf(fmaxf(cd, rmin), rmax);
        out_depth[ray] = cd;
        out_rgb[(size_t)ray * 3 + 0] = sr - 1.0f;   // (0.5*sr)*2 - 1
        out_rgb[(size_t)ray * 3 + 1] = sg - 1.0f;
        out_rgb[(size_t)ray * 3 + 2] = sb - 1.0f;
    }
}

// ---------------------------------------------------------------------------
extern "C" void kernel_launch(void* const* d_in, const int* in_sizes, int n_in,
                              void* d_out, int out_size, void* d_ws, size_t ws_size,
                              hipStream_t stream) {
    const float* colors    = (const float*)d_in[0];
    const float* densities = (const float*)d_in[1];
    const float* depths    = (const float*)d_in[2];

    const int n_rays = in_sizes[1] / NS;

    float* out       = (float*)d_out;
    float* out_rgb   = out;
    float* out_depth = out + (size_t)n_rays * 3;
    float* out_w     = out + (size_t)n_rays * 4;

    hipLaunchKernelGGL(raymarch_kernel,
                       dim3((n_rays + RPB - 1) / RPB), dim3(256), 0, stream,
                       colors, densities, depths,
                       out_rgb, out_depth, out_w, n_rays);
}